// Round 6
// baseline (117.994 us; speedup 1.0000x reference)
//
#include <hip/hip_runtime.h>
#include <hip/hip_bf16.h>
#include <stdint.h>

#define IN_F  4096
#define OUT_F 11008
#define MTOT  512

#define BM 128
#define BN 64
#define BK 64
#define NKT   (IN_F / BK)          // 64 K-tiles total
#define KSPL  2
#define NKT_S (NKT / KSPL)         // 32 K-tiles per split
#define A_TILE_B (BM * BK * 2)     // 16384 B
#define B_TILE_B (BN * BK * 2)     // 8192 B
#define X_WS_BYTES ((size_t)MTOT * IN_F * 2)   // 4 MiB

typedef __attribute__((ext_vector_type(4))) float  f32x4;
typedef __attribute__((ext_vector_type(4))) int    i32x4;
typedef __attribute__((ext_vector_type(2))) unsigned u32x2;
typedef __attribute__((ext_vector_type(4))) unsigned u32x4;
typedef __attribute__((ext_vector_type(8))) __bf16 bf16x8;

// f32 -> bf16 pair, round-to-nearest (for X)
__device__ __forceinline__ unsigned pack2bf16_rnd(float lo, float hi) {
    unsigned ulo = __builtin_bit_cast(unsigned, lo) + 0x8000u;
    unsigned uhi = __builtin_bit_cast(unsigned, hi) + 0x8000u;
    return __builtin_amdgcn_perm(uhi, ulo, 0x07060302u);
}
// f32 -> bf16 pair, truncation (exact for ints |q|<=127)
__device__ __forceinline__ unsigned pack2bf16_exact(float lo, float hi) {
    return __builtin_amdgcn_perm(__builtin_bit_cast(unsigned, hi),
                                 __builtin_bit_cast(unsigned, lo), 0x07060302u);
}

__device__ __forceinline__ void gload_lds16(const void* g, void* l) {
    __builtin_amdgcn_global_load_lds(
        (const __attribute__((address_space(1))) unsigned*)g,
        (__attribute__((address_space(3))) unsigned*)l, 16, 0, 0);
}

// ---- Prepass: X fp32 -> bf16, stored as [mtile][kt][swizzled 16KB tile] ----
// Element (row_l, k_l) of a tile lives at byte p = a ^ ((row_l&7)<<4),
// a = row_l*128 + k_l*2 (involution; matches the GEMM's fragment reads).
__global__ __launch_bounds__(256)
void xconv_kernel(const float* __restrict__ X, char* __restrict__ xws) {
    const int gid  = blockIdx.x * 256 + threadIdx.x;   // 262144 threads
    const int row  = gid >> 9;          // 512 8-elem chunks per row
    const int col0 = (gid & 511) * 8;
    const float* src = X + (size_t)row * IN_F + col0;
    f32x4 v0 = *(const f32x4*)(src);
    f32x4 v1 = *(const f32x4*)(src + 4);
    u32x4 o;
    o.x = pack2bf16_rnd(v0.x, v0.y);
    o.y = pack2bf16_rnd(v0.z, v0.w);
    o.z = pack2bf16_rnd(v1.x, v1.y);
    o.w = pack2bf16_rnd(v1.z, v1.w);
    const int mtile = row >> 7, row_l = row & 127;
    const int kt = col0 >> 6,  k_l  = col0 & 63;
    const int a = row_l * 128 + k_l * 2;
    const int p = a ^ ((row_l & 7) << 4);
    *(u32x4*)(xws + (size_t)mtile * (NKT * A_TILE_B)
                  + (size_t)kt * A_TILE_B + p) = o;
}

// ---- Split-K GEMM: BM=128 x BN=64 x K/2 per block, 2 waves, 64x64 wave tile.
//      A via global_load_lds from xws (dbuf), B reg-staged+converted.
//      Partials combined with atomicAdd into zeroed Out (2 commuting adds
//      per element -> deterministic). Split 0 contributes the bias.
__global__ __launch_bounds__(128, 2)
void qgemm_split_kernel(const char* __restrict__ xws,
                        const int*   __restrict__ W,
                        const float* __restrict__ scale,
                        const float* __restrict__ bias,
                        float* __restrict__ Out)
{
    __shared__ __align__(16) char smem[2 * A_TILE_B + B_TILE_B];  // 40 KiB
    char* bufA0 = smem;
    char* bufA1 = smem + A_TILE_B;
    char* bufB  = smem + 2 * A_TILE_B;

    const int tid  = (int)threadIdx.x;
    const int lane = tid & 63;
    const int w    = tid >> 6;     // wave 0..1 -> rows [w*64, w*64+64)

    // XCD mapping: grid = 1376 = 8*172 exact. Within an XCD, consecutive
    // local ids are the 8 blocks (4 mtiles x 2 ksplits) of one ntile ->
    // the 1 MB W panel is L2-shared 8-way; then the next ntile.
    const int bid  = (int)blockIdx.x;
    const int lbid = (bid & 7) * 172 + (bid >> 3);
    const int kspl  = lbid & 1;        // K split 0..1
    const int mtile = (lbid >> 1) & 3; // M/BM = 4
    const int ntile = lbid >> 3;       // N/BN = 172
    const int brow = mtile * BM;
    const int bcol = ntile * BN;
    const int kt0  = kspl * NKT_S;     // first global k-tile of this split

    // B staging: thread t covers rows (t>>4)+k*8 (k=0..7), i32x4 chunk t&15.
    const int srow  = tid >> 4;    // 0..7
    const int scol4 = tid & 15;    // 0..15
    const int* Wp = W + (size_t)(bcol + srow) * IN_F + (size_t)kt0 * BK + scol4 * 4;

    const char* xsrc = xws + (size_t)mtile * (NKT * A_TILE_B)
                     + (size_t)kt0 * A_TILE_B + w * 8192 + lane * 16;

    i32x4 rb[8];
    f32x4 acc[4][4];
    #pragma unroll
    for (int i = 0; i < 4; ++i)
        #pragma unroll
        for (int j = 0; j < 4; ++j)
            acc[i][j] = (f32x4){0.f, 0.f, 0.f, 0.f};

    // prologue: B(kt0) -> regs; A(kt0) -> bufA0 via DMA
    #pragma unroll
    for (int k = 0; k < 8; ++k)
        rb[k] = *(const i32x4*)(Wp + (size_t)(k * 8) * IN_F);
    #pragma unroll
    for (int c = 0; c < 8; ++c)
        gload_lds16(xsrc + c * 1024, bufA0 + w * 8192 + c * 1024);

    for (int kt = 0; kt < NKT_S; ++kt) {
        char* curA = (kt & 1) ? bufA1 : bufA0;

        // --- phase 1: stage B(kt) from regs (convert int32 -> bf16) ---
        #pragma unroll
        for (int k = 0; k < 8; ++k) {
            const int row = srow + k * 8;
            const int off = (row * 128 + scol4 * 8) ^ ((row & 7) << 4);
            u32x2 bv;
            bv.x = pack2bf16_exact((float)rb[k].x, (float)rb[k].y);
            bv.y = pack2bf16_exact((float)rb[k].z, (float)rb[k].w);
            *(u32x2*)(bufB + off) = bv;
        }
        __syncthreads();   // drains A(kt) DMA (issued last iter) + B writes

        // --- phase 2: issue next-tile loads first (max cover), then MFMA ---
        if (kt + 1 < NKT_S) {
            char* nxtA = (kt & 1) ? bufA0 : bufA1;
            const char* xs = xsrc + (size_t)(kt + 1) * A_TILE_B;
            #pragma unroll
            for (int c = 0; c < 8; ++c)
                gload_lds16(xs + c * 1024, nxtA + w * 8192 + c * 1024);
            const int* Wk = Wp + (size_t)(kt + 1) * BK;
            #pragma unroll
            for (int k = 0; k < 8; ++k)
                rb[k] = *(const i32x4*)(Wk + (size_t)(k * 8) * IN_F);
        }

        // wave tile 64x64: 4 A-frags x 4 B-frags x 2 K-steps = 32 MFMA
        #pragma unroll
        for (int ks = 0; ks < 2; ++ks) {
            bf16x8 af[4], bfr[4];
            #pragma unroll
            for (int mi = 0; mi < 4; ++mi) {
                const int row = w * 64 + mi * 16 + (lane & 15);
                const int off = (row * 128 + ks * 64 + (lane >> 4) * 16)
                                ^ ((row & 7) << 4);
                af[mi] = *(const bf16x8*)(curA + off);
            }
            #pragma unroll
            for (int ni = 0; ni < 4; ++ni) {
                const int row = ni * 16 + (lane & 15);
                const int off = (row * 128 + ks * 64 + (lane >> 4) * 16)
                                ^ ((row & 7) << 4);
                bfr[ni] = *(const bf16x8*)(bufB + off);
            }
            #pragma unroll
            for (int mi = 0; mi < 4; ++mi)
                #pragma unroll
                for (int ni = 0; ni < 4; ++ni)
                    acc[mi][ni] = __builtin_amdgcn_mfma_f32_16x16x32_bf16(
                        af[mi], bfr[ni], acc[mi][ni], 0, 0, 0);
        }
        __syncthreads();   // next-tile DMA/loads drain here (covered by MFMA)
    }

    // --- epilogue: atomicAdd partial; split 0 carries the bias ---
    // C/D mapping: col = lane&15, row = (lane>>4)*4 + j
    #pragma unroll
    for (int ni = 0; ni < 4; ++ni) {
        const int col = bcol + ni * 16 + (lane & 15);
        const float inv = 1.0f / scale[col];
        const float bs  = (kspl == 0) ? bias[col] : 0.0f;
        #pragma unroll
        for (int mi = 0; mi < 4; ++mi) {
            const int row0 = brow + w * 64 + mi * 16 + ((lane >> 4) << 2);
            #pragma unroll
            for (int j = 0; j < 4; ++j) {
                atomicAdd(&Out[(size_t)(row0 + j) * OUT_F + col],
                          acc[mi][ni][j] * inv + bs);
            }
        }
    }
}

// ---- Fallback (ws too small): R5 full-K kernel, plain stores ----
__global__ __launch_bounds__(128, 2)
void qgemm_fallback_kernel(const float* __restrict__ X,
                           const int*   __restrict__ W,
                           const float* __restrict__ scale,
                           const float* __restrict__ bias,
                           float* __restrict__ Out)
{
    __shared__ __align__(16) char smem[A_TILE_B + B_TILE_B];
    char* bufA = smem;
    char* bufB = smem + A_TILE_B;

    const int tid  = (int)threadIdx.x;
    const int lane = tid & 63;
    const int w    = tid >> 6;

    const int bid  = (int)blockIdx.x;
    const int lbid = (bid & 7) * 86 + (bid >> 3);
    const int mtile = lbid & 3;
    const int ntile = lbid >> 2;
    const int brow = mtile * BM;
    const int bcol = ntile * BN;

    const int srow  = tid >> 4;
    const int scol4 = tid & 15;
    const int* Wp = W + (size_t)(bcol + srow) * IN_F + scol4 * 4;
    const float* Xp = X + (size_t)(brow + srow) * IN_F + scol4 * 4;

    f32x4 acc[4][4];
    #pragma unroll
    for (int i = 0; i < 4; ++i)
        #pragma unroll
        for (int j = 0; j < 4; ++j)
            acc[i][j] = (f32x4){0.f, 0.f, 0.f, 0.f};

    for (int kt = 0; kt < NKT; ++kt) {
        #pragma unroll
        for (int k = 0; k < 8; ++k) {
            i32x4 rb = *(const i32x4*)(Wp + (size_t)kt * BK + (size_t)(k * 8) * IN_F);
            const int row = srow + k * 8;
            const int off = (row * 128 + scol4 * 8) ^ ((row & 7) << 4);
            u32x2 bv;
            bv.x = pack2bf16_exact((float)rb.x, (float)rb.y);
            bv.y = pack2bf16_exact((float)rb.z, (float)rb.w);
            *(u32x2*)(bufB + off) = bv;
        }
        #pragma unroll
        for (int k = 0; k < 16; ++k) {
            f32x4 ra = *(const f32x4*)(Xp + (size_t)kt * BK + (size_t)(k * 8) * IN_F);
            const int row = srow + k * 8;
            const int off = (row * 128 + scol4 * 8) ^ ((row & 7) << 4);
            u32x2 av;
            av.x = pack2bf16_rnd(ra.x, ra.y);
            av.y = pack2bf16_rnd(ra.z, ra.w);
            *(u32x2*)(bufA + off) = av;
        }
        __syncthreads();
        #pragma unroll
        for (int ks = 0; ks < 2; ++ks) {
            bf16x8 af[4], bfr[4];
            #pragma unroll
            for (int mi = 0; mi < 4; ++mi) {
                const int row = w * 64 + mi * 16 + (lane & 15);
                const int off = (row * 128 + ks * 64 + (lane >> 4) * 16)
                                ^ ((row & 7) << 4);
                af[mi] = *(const bf16x8*)(bufA + off);
            }
            #pragma unroll
            for (int ni = 0; ni < 4; ++ni) {
                const int row = ni * 16 + (lane & 15);
                const int off = (row * 128 + ks * 64 + (lane >> 4) * 16)
                                ^ ((row & 7) << 4);
                bfr[ni] = *(const bf16x8*)(bufB + off);
            }
            #pragma unroll
            for (int mi = 0; mi < 4; ++mi)
                #pragma unroll
                for (int ni = 0; ni < 4; ++ni)
                    acc[mi][ni] = __builtin_amdgcn_mfma_f32_16x16x32_bf16(
                        af[mi], bfr[ni], acc[mi][ni], 0, 0, 0);
        }
        __syncthreads();
    }

    #pragma unroll
    for (int ni = 0; ni < 4; ++ni) {
        const int col = bcol + ni * 16 + (lane & 15);
        const float inv = 1.0f / scale[col];
        const float bs  = bias[col];
        #pragma unroll
        for (int mi = 0; mi < 4; ++mi) {
            const int row0 = brow + w * 64 + mi * 16 + ((lane >> 4) << 2);
            #pragma unroll
            for (int j = 0; j < 4; ++j)
                Out[(size_t)(row0 + j) * OUT_F + col] = acc[mi][ni][j] * inv + bs;
        }
    }
}

extern "C" void kernel_launch(void* const* d_in, const int* in_sizes, int n_in,
                              void* d_out, int out_size, void* d_ws, size_t ws_size,
                              hipStream_t stream) {
    const float* X     = (const float*)d_in[0];
    const int*   W     = (const int*)d_in[1];
    const float* scale = (const float*)d_in[2];
    const float* bias  = (const float*)d_in[3];
    float* Out = (float*)d_out;

    if (ws_size >= X_WS_BYTES) {
        char* xws = (char*)d_ws;
        // Out must start at zero for the atomic split-K combine.
        hipMemsetAsync(Out, 0, (size_t)out_size * sizeof(float), stream);
        xconv_kernel<<<(MTOT * IN_F / 8) / 256, 256, 0, stream>>>(X, xws);
        const int grid = (MTOT / BM) * (OUT_F / BN) * KSPL;  // 1376 = 8*172
        qgemm_split_kernel<<<grid, 128, 0, stream>>>(xws, W, scale, bias, Out);
    } else {
        const int grid = (MTOT / BM) * (OUT_F / BN);  // 688
        qgemm_fallback_kernel<<<grid, 128, 0, stream>>>(X, W, scale, bias, Out);
    }
}

// Round 7
// 85.705 us; speedup vs baseline: 1.3767x; 1.3767x over previous
//
#include <hip/hip_runtime.h>
#include <hip/hip_bf16.h>
#include <stdint.h>

#define IN_F  4096
#define OUT_F 11008
#define MTOT  512

#define BM 128
#define BN 64
#define BK 64
#define NKT (IN_F / BK)            // 64 K-tiles
#define A_TILE_B (BM * BK * 2)     // 16384 B
#define B_TILE_B (BN * BK * 2)     // 8192 B
#define X_WS_BYTES ((size_t)MTOT * IN_F * 2)   // 4 MiB

typedef __attribute__((ext_vector_type(4))) float  f32x4;
typedef __attribute__((ext_vector_type(4))) int    i32x4;
typedef __attribute__((ext_vector_type(2))) unsigned u32x2;
typedef __attribute__((ext_vector_type(4))) unsigned u32x4;
typedef __attribute__((ext_vector_type(8))) __bf16 bf16x8;

// f32 -> bf16 pair, round-to-nearest (for X)
__device__ __forceinline__ unsigned pack2bf16_rnd(float lo, float hi) {
    unsigned ulo = __builtin_bit_cast(unsigned, lo) + 0x8000u;
    unsigned uhi = __builtin_bit_cast(unsigned, hi) + 0x8000u;
    return __builtin_amdgcn_perm(uhi, ulo, 0x07060302u);
}
// f32 -> bf16 pair, truncation (exact for ints |q|<=127)
__device__ __forceinline__ unsigned pack2bf16_exact(float lo, float hi) {
    return __builtin_amdgcn_perm(__builtin_bit_cast(unsigned, hi),
                                 __builtin_bit_cast(unsigned, lo), 0x07060302u);
}

__device__ __forceinline__ void gload_lds16(const void* g, void* l) {
    __builtin_amdgcn_global_load_lds(
        (const __attribute__((address_space(1))) unsigned*)g,
        (__attribute__((address_space(3))) unsigned*)l, 16, 0, 0);
}

// Counted-vmcnt barrier: drains the 8 A-DMA ops (oldest) + all LDS writes,
// leaves the 8 younger B register-loads in flight across the barrier.
// Safe: only private-register loads are exempt from the drain.
#define BARRIER_VM(N) do {                                         \
    asm volatile("s_waitcnt vmcnt(" #N ") lgkmcnt(0)" ::: "memory"); \
    __builtin_amdgcn_s_barrier();                                  \
    __builtin_amdgcn_sched_barrier(0);                             \
} while (0)

// ---- Prepass: X fp32 -> bf16, stored as [mtile][kt][swizzled 16KB tile] ----
__global__ __launch_bounds__(256)
void xconv_kernel(const float* __restrict__ X, char* __restrict__ xws) {
    const int gid  = blockIdx.x * 256 + threadIdx.x;   // 262144 threads
    const int row  = gid >> 9;
    const int col0 = (gid & 511) * 8;
    const float* src = X + (size_t)row * IN_F + col0;
    f32x4 v0 = *(const f32x4*)(src);
    f32x4 v1 = *(const f32x4*)(src + 4);
    u32x4 o;
    o.x = pack2bf16_rnd(v0.x, v0.y);
    o.y = pack2bf16_rnd(v0.z, v0.w);
    o.z = pack2bf16_rnd(v1.x, v1.y);
    o.w = pack2bf16_rnd(v1.z, v1.w);
    const int mtile = row >> 7, row_l = row & 127;
    const int kt = col0 >> 6,  k_l  = col0 & 63;
    const int a = row_l * 128 + k_l * 2;
    const int p = a ^ ((row_l & 7) << 4);
    *(u32x4*)(xws + (size_t)mtile * (NKT * A_TILE_B)
                  + (size_t)kt * A_TILE_B + p) = o;
}

// ---- Main GEMM: BM=128 x BN=64, 2 waves, 64x64 wave tile.
//      Single s_barrier per K-tile, counted vmcnt; A+B LDS double-buffered;
//      B register pipeline 2 tiles deep (named even/odd sets). ----
__global__ __launch_bounds__(128, 2)
void qgemm_kernel(const char* __restrict__ xws,
                  const int*   __restrict__ W,
                  const float* __restrict__ scale,
                  const float* __restrict__ bias,
                  float* __restrict__ Out)
{
    __shared__ __align__(16) char smem[2 * (A_TILE_B + B_TILE_B)];  // 48 KiB
    char* bufA[2] = { smem,                smem + A_TILE_B };
    char* bufB[2] = { smem + 2 * A_TILE_B, smem + 2 * A_TILE_B + B_TILE_B };

    const int tid  = (int)threadIdx.x;
    const int lane = tid & 63;
    const int w    = tid >> 6;

    // XCD mapping (R2/R5-proven): 688 = 8*86 exact; the 4 mtiles of one ntile
    // are consecutive within an XCD -> 1 MB W panel L2-shared 4-way.
    const int bid  = (int)blockIdx.x;
    const int lbid = (bid & 7) * 86 + (bid >> 3);
    const int mtile = lbid & 3;
    const int ntile = lbid >> 2;
    const int brow = mtile * BM;
    const int bcol = ntile * BN;

    const int srow  = tid >> 4;    // 0..7
    const int scol4 = tid & 15;    // 0..15
    const int* Wp = W + (size_t)(bcol + srow) * IN_F + scol4 * 4;

    const char* xsrc = xws + (size_t)mtile * (NKT * A_TILE_B)
                     + w * 8192 + lane * 16;

    i32x4 rbE[8], rbO[8];
    f32x4 acc[4][4];
    #pragma unroll
    for (int i = 0; i < 4; ++i)
        #pragma unroll
        for (int j = 0; j < 4; ++j)
            acc[i][j] = (f32x4){0.f, 0.f, 0.f, 0.f};

    // ---------- prologue ----------
    // B(0) -> regs -> convert -> bufB0 (compiler waits the loads)
    #pragma unroll
    for (int k = 0; k < 8; ++k)
        rbE[k] = *(const i32x4*)(Wp + (size_t)(k * 8) * IN_F);
    #pragma unroll
    for (int k = 0; k < 8; ++k) {
        const int row = srow + k * 8;
        const int off = (row * 128 + scol4 * 8) ^ ((row & 7) << 4);
        u32x2 bv;
        bv.x = pack2bf16_exact((float)rbE[k].x, (float)rbE[k].y);
        bv.y = pack2bf16_exact((float)rbE[k].z, (float)rbE[k].w);
        *(u32x2*)(bufB[0] + off) = bv;
    }
    // A(0) DMA (oldest 8 vmem), then B(1) loads (younger 8)
    #pragma unroll
    for (int c = 0; c < 8; ++c)
        gload_lds16(xsrc + c * 1024, bufA[0] + w * 8192 + c * 1024);
    #pragma unroll
    for (int k = 0; k < 8; ++k)
        rbE[k] = *(const i32x4*)(Wp + BK + (size_t)(k * 8) * IN_F);
    BARRIER_VM(8);   // A(0) DMA + ds_writes drained; B(1) in flight

    // ---------- main loop: pairs (even kt, odd kt+1) ----------
    // Invariant at even-iter top: buf[kt&1] holds tile kt; rbE holds B(kt+1).
    #define MFMA_PHASE(PB)                                                   \
        _Pragma("unroll")                                                    \
        for (int ks = 0; ks < 2; ++ks) {                                     \
            bf16x8 af[4], bfr[4];                                            \
            _Pragma("unroll")                                                \
            for (int mi = 0; mi < 4; ++mi) {                                 \
                const int row = w * 64 + mi * 16 + (lane & 15);              \
                const int off = (row * 128 + ks * 64 + (lane >> 4) * 16)     \
                                ^ ((row & 7) << 4);                          \
                af[mi] = *(const bf16x8*)(bufA[PB] + off);                   \
            }                                                                \
            _Pragma("unroll")                                                \
            for (int ni = 0; ni < 4; ++ni) {                                 \
                const int row = ni * 16 + (lane & 15);                       \
                const int off = (row * 128 + ks * 64 + (lane >> 4) * 16)     \
                                ^ ((row & 7) << 4);                          \
                bfr[ni] = *(const bf16x8*)(bufB[PB] + off);                  \
            }                                                                \
            _Pragma("unroll")                                                \
            for (int mi = 0; mi < 4; ++mi)                                   \
                _Pragma("unroll")                                            \
                for (int ni = 0; ni < 4; ++ni)                               \
                    acc[mi][ni] = __builtin_amdgcn_mfma_f32_16x16x32_bf16(   \
                        af[mi], bfr[ni], acc[mi][ni], 0, 0, 0);              \
        }

    #define CONVERT_B(RB, DSTB)                                              \
        _Pragma("unroll")                                                    \
        for (int k = 0; k < 8; ++k) {                                        \
            const int row = srow + k * 8;                                    \
            const int off = (row * 128 + scol4 * 8) ^ ((row & 7) << 4);      \
            u32x2 bv;                                                        \
            bv.x = pack2bf16_exact((float)RB[k].x, (float)RB[k].y);          \
            bv.y = pack2bf16_exact((float)RB[k].z, (float)RB[k].w);          \
            *(u32x2*)((DSTB) + off) = bv;                                    \
        }

    for (int kt2 = 0; kt2 < NKT; kt2 += 2) {
        const bool last_pair = (kt2 == NKT - 2);

        // ===== even iter kt = kt2: compute buf0, fill buf1 =====
        {
            // 1. A(kt+1) DMA -> bufA1 (oldest vmem this iter)
            const char* xs = xsrc + (size_t)(kt2 + 1) * A_TILE_B;
            #pragma unroll
            for (int c = 0; c < 8; ++c)
                gload_lds16(xs + c * 1024, bufA[1] + w * 8192 + c * 1024);
            // 2. B(kt+2) -> rbO (skipped on last pair)
            if (!last_pair) {
                const int* Wk = Wp + (size_t)(kt2 + 2) * BK;
                #pragma unroll
                for (int k = 0; k < 8; ++k)
                    rbO[k] = *(const i32x4*)(Wk + (size_t)(k * 8) * IN_F);
            }
            // 3. convert B(kt+1) from rbE -> bufB1
            CONVERT_B(rbE, bufB[1]);
            // 4. MFMA on tile kt (buf0)
            MFMA_PHASE(0);
            // 5. publish buf1
            if (!last_pair) { BARRIER_VM(8); } else { BARRIER_VM(0); }
        }

        // ===== odd iter kt = kt2+1: compute buf1, fill buf0 =====
        {
            if (!last_pair) {
                // 1. A(kt+1) DMA -> bufA0
                const char* xs = xsrc + (size_t)(kt2 + 2) * A_TILE_B;
                #pragma unroll
                for (int c = 0; c < 8; ++c)
                    gload_lds16(xs + c * 1024, bufA[0] + w * 8192 + c * 1024);
                // 2. B(kt+3) -> rbE
                const int* Wk = Wp + (size_t)(kt2 + 3) * BK;
                #pragma unroll
                for (int k = 0; k < 8; ++k)
                    rbE[k] = *(const i32x4*)(Wk + (size_t)(k * 8) * IN_F);
                // 3. convert B(kt+2) from rbO -> bufB0
                CONVERT_B(rbO, bufB[0]);
            }
            // 4. MFMA on tile kt (buf1)
            MFMA_PHASE(1);
            // 5. publish buf0 (not needed after the final tile)
            if (!last_pair) { BARRIER_VM(8); }
        }
    }

    // --- epilogue: out = acc / scale[col] + bias[col] ---
    // C/D mapping: col = lane&15, row = (lane>>4)*4 + j
    #pragma unroll
    for (int ni = 0; ni < 4; ++ni) {
        const int col = bcol + ni * 16 + (lane & 15);
        const float inv = 1.0f / scale[col];
        const float bs  = bias[col];
        #pragma unroll
        for (int mi = 0; mi < 4; ++mi) {
            const int row0 = brow + w * 64 + mi * 16 + ((lane >> 4) << 2);
            #pragma unroll
            for (int j = 0; j < 4; ++j)
                Out[(size_t)(row0 + j) * OUT_F + col] = acc[mi][ni][j] * inv + bs;
        }
    }
}

// ---- Fallback (ws too small): R5 full-K kernel, plain stores ----
__global__ __launch_bounds__(128, 2)
void qgemm_fallback_kernel(const float* __restrict__ X,
                           const int*   __restrict__ W,
                           const float* __restrict__ scale,
                           const float* __restrict__ bias,
                           float* __restrict__ Out)
{
    __shared__ __align__(16) char smem[A_TILE_B + B_TILE_B];
    char* bufA = smem;
    char* bufB = smem + A_TILE_B;

    const int tid  = (int)threadIdx.x;
    const int lane = tid & 63;
    const int w    = tid >> 6;

    const int bid  = (int)blockIdx.x;
    const int lbid = (bid & 7) * 86 + (bid >> 3);
    const int mtile = lbid & 3;
    const int ntile = lbid >> 2;
    const int brow = mtile * BM;
    const int bcol = ntile * BN;

    const int srow  = tid >> 4;
    const int scol4 = tid & 15;
    const int* Wp = W + (size_t)(bcol + srow) * IN_F + scol4 * 4;
    const float* Xp = X + (size_t)(brow + srow) * IN_F + scol4 * 4;

    f32x4 acc[4][4];
    #pragma unroll
    for (int i = 0; i < 4; ++i)
        #pragma unroll
        for (int j = 0; j < 4; ++j)
            acc[i][j] = (f32x4){0.f, 0.f, 0.f, 0.f};

    for (int kt = 0; kt < NKT; ++kt) {
        #pragma unroll
        for (int k = 0; k < 8; ++k) {
            i32x4 rb = *(const i32x4*)(Wp + (size_t)kt * BK + (size_t)(k * 8) * IN_F);
            const int row = srow + k * 8;
            const int off = (row * 128 + scol4 * 8) ^ ((row & 7) << 4);
            u32x2 bv;
            bv.x = pack2bf16_exact((float)rb.x, (float)rb.y);
            bv.y = pack2bf16_exact((float)rb.z, (float)rb.w);
            *(u32x2*)(bufB + off) = bv;
        }
        #pragma unroll
        for (int k = 0; k < 16; ++k) {
            f32x4 ra = *(const f32x4*)(Xp + (size_t)kt * BK + (size_t)(k * 8) * IN_F);
            const int row = srow + k * 8;
            const int off = (row * 128 + scol4 * 8) ^ ((row & 7) << 4);
            u32x2 av;
            av.x = pack2bf16_rnd(ra.x, ra.y);
            av.y = pack2bf16_rnd(ra.z, ra.w);
            *(u32x2*)(bufA + off) = av;
        }
        __syncthreads();
        #pragma unroll
        for (int ks = 0; ks < 2; ++ks) {
            bf16x8 af[4], bfr[4];
            #pragma unroll
            for (int mi = 0; mi < 4; ++mi) {
                const int row = w * 64 + mi * 16 + (lane & 15);
                const int off = (row * 128 + ks * 64 + (lane >> 4) * 16)
                                ^ ((row & 7) << 4);
                af[mi] = *(const bf16x8*)(bufA + off);
            }
            #pragma unroll
            for (int ni = 0; ni < 4; ++ni) {
                const int row = ni * 16 + (lane & 15);
                const int off = (row * 128 + ks * 64 + (lane >> 4) * 16)
                                ^ ((row & 7) << 4);
                bfr[ni] = *(const bf16x8*)(bufB + off);
            }
            #pragma unroll
            for (int mi = 0; mi < 4; ++mi)
                #pragma unroll
                for (int ni = 0; ni < 4; ++ni)
                    acc[mi][ni] = __builtin_amdgcn_mfma_f32_16x16x32_bf16(
                        af[mi], bfr[ni], acc[mi][ni], 0, 0, 0);
        }
        __syncthreads();
    }

    #pragma unroll
    for (int ni = 0; ni < 4; ++ni) {
        const int col = bcol + ni * 16 + (lane & 15);
        const float inv = 1.0f / scale[col];
        const float bs  = bias[col];
        #pragma unroll
        for (int mi = 0; mi < 4; ++mi) {
            const int row0 = brow + w * 64 + mi * 16 + ((lane >> 4) << 2);
            #pragma unroll
            for (int j = 0; j < 4; ++j)
                Out[(size_t)(row0 + j) * OUT_F + col] = acc[mi][ni][j] * inv + bs;
        }
    }
}

extern "C" void kernel_launch(void* const* d_in, const int* in_sizes, int n_in,
                              void* d_out, int out_size, void* d_ws, size_t ws_size,
                              hipStream_t stream) {
    const float* X     = (const float*)d_in[0];
    const int*   W     = (const int*)d_in[1];
    const float* scale = (const float*)d_in[2];
    const float* bias  = (const float*)d_in[3];
    float* Out = (float*)d_out;

    const int grid = (MTOT / BM) * (OUT_F / BN);  // 688 = 8*86

    if (ws_size >= X_WS_BYTES) {
        char* xws = (char*)d_ws;
        xconv_kernel<<<(MTOT * IN_F / 8) / 256, 256, 0, stream>>>(X, xws);
        qgemm_kernel<<<grid, 128, 0, stream>>>(xws, W, scale, bias, Out);
    } else {
        qgemm_fallback_kernel<<<grid, 128, 0, stream>>>(X, W, scale, bias, Out);
    }
}

// Round 8
// 76.406 us; speedup vs baseline: 1.5443x; 1.1217x over previous
//
#include <hip/hip_runtime.h>
#include <hip/hip_bf16.h>
#include <stdint.h>

#define IN_F  4096
#define OUT_F 11008
#define MTOT  512

#define BM 128
#define BN 64
#define BK 64
#define NKT (IN_F / BK)            // 64 K-tiles
#define B_TILE_B (BN * BK * 2)     // 8192 B
#define XT_B 16384                 // per [mtile][kt] fragment block: 16 frags x 1 KB
#define X_WS_BYTES ((size_t)MTOT * IN_F * 2)   // 4 MiB

typedef __attribute__((ext_vector_type(4))) float  f32x4;
typedef __attribute__((ext_vector_type(4))) int    i32x4;
typedef __attribute__((ext_vector_type(2))) unsigned u32x2;
typedef __attribute__((ext_vector_type(4))) unsigned u32x4;
typedef __attribute__((ext_vector_type(8))) __bf16 bf16x8;

// f32 -> bf16 pair, round-to-nearest (for X)
__device__ __forceinline__ unsigned pack2bf16_rnd(float lo, float hi) {
    unsigned ulo = __builtin_bit_cast(unsigned, lo) + 0x8000u;
    unsigned uhi = __builtin_bit_cast(unsigned, hi) + 0x8000u;
    return __builtin_amdgcn_perm(uhi, ulo, 0x07060302u);
}
// f32 -> bf16 pair, truncation (exact for ints |q|<=127)
__device__ __forceinline__ unsigned pack2bf16_exact(float lo, float hi) {
    return __builtin_amdgcn_perm(__builtin_bit_cast(unsigned, hi),
                                 __builtin_bit_cast(unsigned, lo), 0x07060302u);
}

// LDS-only barrier: B ds_writes/ds_reads are the only cross-wave state.
// Global loads (A-frags, raw B) stay in flight across it by design.
#define BAR() do {                                                 \
    asm volatile("s_waitcnt lgkmcnt(0)" ::: "memory");             \
    __builtin_amdgcn_s_barrier();                                  \
    __builtin_amdgcn_sched_barrier(0);                             \
} while (0)

// ---- Prepass: X fp32 -> bf16 in MFMA-FRAGMENT order ----
// xws layout: [mtile][kt][f = mi*2+ks][lane][16B], 16 KB per (mtile,kt).
// Lane l of frag (mi,ks) holds X[mtile*128 + mi*16 + (l&15)]
//                              [kt*64 + ks*32 + (l>>4)*8 .. +8] as bf16x8.
__global__ __launch_bounds__(256)
void xconv_kernel(const float* __restrict__ X, char* __restrict__ xws) {
    const int gid  = blockIdx.x * 256 + threadIdx.x;   // 262144 threads
    const int row  = gid >> 9;          // 0..511
    const int col0 = (gid & 511) * 8;   // 8-aligned column
    const float* src = X + (size_t)row * IN_F + col0;
    f32x4 v0 = *(const f32x4*)(src);
    f32x4 v1 = *(const f32x4*)(src + 4);
    u32x4 o;
    o.x = pack2bf16_rnd(v0.x, v0.y);
    o.y = pack2bf16_rnd(v0.z, v0.w);
    o.z = pack2bf16_rnd(v1.x, v1.y);
    o.w = pack2bf16_rnd(v1.z, v1.w);
    const int mtile = row >> 7, mrow = row & 127;
    const int mi = mrow >> 4,  l15 = mrow & 15;
    const int kt  = col0 >> 6;
    const int ks  = (col0 >> 5) & 1;
    const int lhi = (col0 >> 3) & 3;
    const int lane = lhi * 16 + l15;
    const int f = mi * 2 + ks;
    *(u32x4*)(xws + ((size_t)(mtile * NKT + kt) * 16 + f) * 1024
                  + lane * 16) = o;
}

// ---- Main GEMM: BM=128 x BN=64, 2 waves, 64x64 wave tile.
//      A: fragment-direct global->reg from xws (L2-resident), no LDS.
//      B: reg-staged + converted into LDS dbuf (only LDS user).
//      One lgkm-only barrier per K-tile; A/B pipelined one tile ahead. ----
__global__ __launch_bounds__(128, 2)
void qgemm_kernel(const char* __restrict__ xws,
                  const int*   __restrict__ W,
                  const float* __restrict__ scale,
                  const float* __restrict__ bias,
                  float* __restrict__ Out)
{
    __shared__ __align__(16) char smem[2 * B_TILE_B];  // 16 KiB
    char* bufB0 = smem;
    char* bufB1 = smem + B_TILE_B;

    const int tid  = (int)threadIdx.x;
    const int lane = tid & 63;
    const int w    = tid >> 6;

    // XCD mapping (R2/R5-proven): 688 = 8*86 exact; the 4 mtiles of one ntile
    // are consecutive within an XCD -> 1 MB W panel L2-shared 4-way.
    const int bid  = (int)blockIdx.x;
    const int lbid = (bid & 7) * 86 + (bid >> 3);
    const int mtile = lbid & 3;
    const int ntile = lbid >> 2;
    const int brow = mtile * BM;
    const int bcol = ntile * BN;

    const int srow  = tid >> 4;    // 0..7
    const int scol4 = tid & 15;    // 0..15
    const int* Wp = W + (size_t)(bcol + srow) * IN_F + scol4 * 4;

    // Wave w owns frags f = (w*4+mi)*2+ks -> base offset w*8192.
    const char* xAw = xws + (size_t)mtile * (NKT * XT_B) + w * 8192 + lane * 16;

    i32x4 rb[8];
    bf16x8 afE[8], afO[8];
    f32x4 acc[4][4];
    #pragma unroll
    for (int i = 0; i < 4; ++i)
        #pragma unroll
        for (int j = 0; j < 4; ++j)
            acc[i][j] = (f32x4){0.f, 0.f, 0.f, 0.f};

    #define LOAD_A(AF, KT)                                                   \
        _Pragma("unroll")                                                    \
        for (int q = 0; q < 8; ++q)                                          \
            AF[q] = *(const bf16x8*)(xAw + (size_t)(KT) * XT_B + q * 1024);

    #define LOAD_B(KT)                                                       \
        _Pragma("unroll")                                                    \
        for (int k = 0; k < 8; ++k)                                          \
            rb[k] = *(const i32x4*)(Wp + (size_t)(KT) * BK                   \
                                       + (size_t)(k * 8) * IN_F);

    #define CONVERT_B(DSTB)                                                  \
        _Pragma("unroll")                                                    \
        for (int k = 0; k < 8; ++k) {                                        \
            const int row = srow + k * 8;                                    \
            const int off = (row * 128 + scol4 * 8) ^ ((row & 7) << 4);      \
            u32x2 bv;                                                        \
            bv.x = pack2bf16_exact((float)rb[k].x, (float)rb[k].y);          \
            bv.y = pack2bf16_exact((float)rb[k].z, (float)rb[k].w);          \
            *(u32x2*)((DSTB) + off) = bv;                                    \
        }

    #define MFMA_PHASE(AF, BUFB)                                             \
        _Pragma("unroll")                                                    \
        for (int ks = 0; ks < 2; ++ks) {                                     \
            bf16x8 bfr[4];                                                   \
            _Pragma("unroll")                                                \
            for (int ni = 0; ni < 4; ++ni) {                                 \
                const int row = ni * 16 + (lane & 15);                       \
                const int off = (row * 128 + ks * 64 + (lane >> 4) * 16)     \
                                ^ ((row & 7) << 4);                          \
                bfr[ni] = *(const bf16x8*)((BUFB) + off);                    \
            }                                                                \
            _Pragma("unroll")                                                \
            for (int mi = 0; mi < 4; ++mi)                                   \
                _Pragma("unroll")                                            \
                for (int ni = 0; ni < 4; ++ni)                               \
                    acc[mi][ni] = __builtin_amdgcn_mfma_f32_16x16x32_bf16(   \
                        AF[mi * 2 + ks], bfr[ni], acc[mi][ni], 0, 0, 0);     \
        }

    // ---------- prologue ----------
    LOAD_B(0);
    CONVERT_B(bufB0);          // compiler waits the rb loads
    LOAD_A(afE, 0);
    LOAD_B(1);
    BAR();                     // publish bufB0

    // ---------- main loop: pairs (even kt2, odd kt2+1) ----------
    // Even-iter invariant: bufB0 = B(kt2); rb = raw B(kt2+1); afE = A(kt2).
    for (int kt2 = 0; kt2 < NKT; kt2 += 2) {
        const bool last = (kt2 == NKT - 2);

        // ===== even kt = kt2: compute bufB0/afE, fill bufB1 =====
        LOAD_A(afO, kt2 + 1);
        CONVERT_B(bufB1);             // B(kt2+1) from rb
        if (!last) LOAD_B(kt2 + 2);
        MFMA_PHASE(afE, bufB0);
        BAR();                        // publish bufB1

        // ===== odd kt = kt2+1: compute bufB1/afO, fill bufB0 =====
        if (!last) {
            LOAD_A(afE, kt2 + 2);
            CONVERT_B(bufB0);         // B(kt2+2) from rb
            LOAD_B(kt2 + 3);
        }
        MFMA_PHASE(afO, bufB1);
        if (!last) BAR();             // publish bufB0
    }

    // --- epilogue: out = acc / scale[col] + bias[col] ---
    // C/D mapping: col = lane&15, row = (lane>>4)*4 + j
    #pragma unroll
    for (int ni = 0; ni < 4; ++ni) {
        const int col = bcol + ni * 16 + (lane & 15);
        const float inv = 1.0f / scale[col];
        const float bs  = bias[col];
        #pragma unroll
        for (int mi = 0; mi < 4; ++mi) {
            const int row0 = brow + w * 64 + mi * 16 + ((lane >> 4) << 2);
            #pragma unroll
            for (int j = 0; j < 4; ++j)
                Out[(size_t)(row0 + j) * OUT_F + col] = acc[mi][ni][j] * inv + bs;
        }
    }

    #undef LOAD_A
    #undef LOAD_B
    #undef CONVERT_B
    #undef MFMA_PHASE
}

// ---- Fallback (ws too small): R5 full-K kernel, LDS-staged both operands ----
__global__ __launch_bounds__(128, 2)
void qgemm_fallback_kernel(const float* __restrict__ X,
                           const int*   __restrict__ W,
                           const float* __restrict__ scale,
                           const float* __restrict__ bias,
                           float* __restrict__ Out)
{
    __shared__ __align__(16) char smem[BM * BK * 2 + B_TILE_B];
    char* bufA = smem;
    char* bufB = smem + BM * BK * 2;

    const int tid  = (int)threadIdx.x;
    const int lane = tid & 63;
    const int w    = tid >> 6;

    const int bid  = (int)blockIdx.x;
    const int lbid = (bid & 7) * 86 + (bid >> 3);
    const int mtile = lbid & 3;
    const int ntile = lbid >> 2;
    const int brow = mtile * BM;
    const int bcol = ntile * BN;

    const int srow  = tid >> 4;
    const int scol4 = tid & 15;
    const int* Wp = W + (size_t)(bcol + srow) * IN_F + scol4 * 4;
    const float* Xp = X + (size_t)(brow + srow) * IN_F + scol4 * 4;

    f32x4 acc[4][4];
    #pragma unroll
    for (int i = 0; i < 4; ++i)
        #pragma unroll
        for (int j = 0; j < 4; ++j)
            acc[i][j] = (f32x4){0.f, 0.f, 0.f, 0.f};

    for (int kt = 0; kt < NKT; ++kt) {
        #pragma unroll
        for (int k = 0; k < 8; ++k) {
            i32x4 rb = *(const i32x4*)(Wp + (size_t)kt * BK + (size_t)(k * 8) * IN_F);
            const int row = srow + k * 8;
            const int off = (row * 128 + scol4 * 8) ^ ((row & 7) << 4);
            u32x2 bv;
            bv.x = pack2bf16_exact((float)rb.x, (float)rb.y);
            bv.y = pack2bf16_exact((float)rb.z, (float)rb.w);
            *(u32x2*)(bufB + off) = bv;
        }
        #pragma unroll
        for (int k = 0; k < 16; ++k) {
            f32x4 ra = *(const f32x4*)(Xp + (size_t)kt * BK + (size_t)(k * 8) * IN_F);
            const int row = srow + k * 8;
            const int off = (row * 128 + scol4 * 8) ^ ((row & 7) << 4);
            u32x2 av;
            av.x = pack2bf16_rnd(ra.x, ra.y);
            av.y = pack2bf16_rnd(ra.z, ra.w);
            *(u32x2*)(bufA + off) = av;
        }
        __syncthreads();
        #pragma unroll
        for (int ks = 0; ks < 2; ++ks) {
            bf16x8 af[4], bfr[4];
            #pragma unroll
            for (int mi = 0; mi < 4; ++mi) {
                const int row = w * 64 + mi * 16 + (lane & 15);
                const int off = (row * 128 + ks * 64 + (lane >> 4) * 16)
                                ^ ((row & 7) << 4);
                af[mi] = *(const bf16x8*)(bufA + off);
            }
            #pragma unroll
            for (int ni = 0; ni < 4; ++ni) {
                const int row = ni * 16 + (lane & 15);
                const int off = (row * 128 + ks * 64 + (lane >> 4) * 16)
                                ^ ((row & 7) << 4);
                bfr[ni] = *(const bf16x8*)(bufB + off);
            }
            #pragma unroll
            for (int mi = 0; mi < 4; ++mi)
                #pragma unroll
                for (int ni = 0; ni < 4; ++ni)
                    acc[mi][ni] = __builtin_amdgcn_mfma_f32_16x16x32_bf16(
                        af[mi], bfr[ni], acc[mi][ni], 0, 0, 0);
        }
        __syncthreads();
    }

    #pragma unroll
    for (int ni = 0; ni < 4; ++ni) {
        const int col = bcol + ni * 16 + (lane & 15);
        const float inv = 1.0f / scale[col];
        const float bs  = bias[col];
        #pragma unroll
        for (int mi = 0; mi < 4; ++mi) {
            const int row0 = brow + w * 64 + mi * 16 + ((lane >> 4) << 2);
            #pragma unroll
            for (int j = 0; j < 4; ++j)
                Out[(size_t)(row0 + j) * OUT_F + col] = acc[mi][ni][j] * inv + bs;
        }
    }
}

extern "C" void kernel_launch(void* const* d_in, const int* in_sizes, int n_in,
                              void* d_out, int out_size, void* d_ws, size_t ws_size,
                              hipStream_t stream) {
    const float* X     = (const float*)d_in[0];
    const int*   W     = (const int*)d_in[1];
    const float* scale = (const float*)d_in[2];
    const float* bias  = (const float*)d_in[3];
    float* Out = (float*)d_out;

    const int grid = (MTOT / BM) * (OUT_F / BN);  // 688 = 8*86

    if (ws_size >= X_WS_BYTES) {
        char* xws = (char*)d_ws;
        xconv_kernel<<<(MTOT * IN_F / 8) / 256, 256, 0, stream>>>(X, xws);
        qgemm_kernel<<<grid, 128, 0, stream>>>(xws, W, scale, bias, Out);
    } else {
        qgemm_fallback_kernel<<<grid, 128, 0, stream>>>(X, W, scale, bias, Out);
    }
}